// Round 1
// 1096.968 us; speedup vs baseline: 1.2653x; 1.2653x over previous
//
#include <hip/hip_runtime.h>
#include <hip/hip_bf16.h>
#include <math.h>
#include <cstdint>

// ---------------------------------------------------------------------------
// 3-layer MLP (Linear+GELU ×3), bf16 MFMA compute, fp32 in/out.
//
// R1 changes vs baseline (latency-bound: MfmaUtil 9%, HBM 26%, all pipes idle):
//  1. 2-phase double-buffered pipeline (catalog T3-minimum): issue next tile's
//     staging BEFORE computing current tile; single __syncthreads per iter
//     placed AFTER the MFMAs so the vmcnt(0) drain hides under compute.
//  2. fp32-A path gets the T14 split: global float4 loads issued at iter top,
//     cvt + swizzled ds_write AFTER the MFMA phase (HBM latency under MFMA).
//  3. T1 chunked XCD remap: the 4 column-blocks sharing an A row-panel land
//     on the same XCD -> L2 dedups A re-reads (FETCH was 2x obs size).
//  4. Epilogue loop reorder (j innermost): 4 adjacent 32B stores per row
//     back-to-back -> L2 write-combining (WRITE was 1.7x ideal).
//
// LDS layout per buffer unchanged: (row,k) -> row*64 + ((k>>3 ^ (row&7))<<3)+(k&7)
// ---------------------------------------------------------------------------

typedef __bf16 bf16_t;
typedef __attribute__((ext_vector_type(8))) __bf16 bf16x8;
typedef __attribute__((ext_vector_type(4))) float f32x4;
typedef __attribute__((ext_vector_type(4))) unsigned short u16x4;

#define BM 128
#define BN 128
#define BK 64

__device__ inline unsigned short f2bf_rne(float f) {
    unsigned int u = __builtin_bit_cast(unsigned int, f);
    u += 0x7fffu + ((u >> 16) & 1u);   // round-to-nearest-even
    return (unsigned short)(u >> 16);
}

__device__ inline float gelu_erf(float x) {
    return 0.5f * x * (1.0f + erff(x * 0.7071067811865475f));
}

__device__ inline void gload_lds16(const void* g, void* l) {
    auto gp = reinterpret_cast<const __attribute__((address_space(1))) unsigned int*>(
        reinterpret_cast<uintptr_t>(g));
    auto lp = reinterpret_cast<__attribute__((address_space(3))) unsigned int*>(
        reinterpret_cast<uintptr_t>(l));
    __builtin_amdgcn_global_load_lds(gp, lp, 16, 0, 0);
}

// C = gelu(A[M,K] @ B[N,K]^T + bias), A fp32 or bf16, C bf16 or fp32.
// Grid: (N/BN, M/BM)  -- column index FAST for A-tile temporal locality.
template <bool A_IS_FP32, bool OUT_BF16>
__global__ __launch_bounds__(256, 2)
void gemm_bias_gelu(const void* __restrict__ Av,
                    const bf16_t* __restrict__ B,     // [N,K] bf16
                    const float* __restrict__ bias,   // [N]
                    void* __restrict__ Cv,            // [M,N]
                    int M, int N, int K)
{
    __shared__ __align__(16) bf16_t lA[2][BM * BK];   // 2 x 16 KiB
    __shared__ __align__(16) bf16_t lB[2][BN * BK];   // 2 x 16 KiB

    const int tid  = threadIdx.x;
    const int wave = tid >> 6;
    const int lane = tid & 63;
    const int lrow = lane & 15;   // MFMA row/col within 16
    const int quad = lane >> 4;   // k-group of 8
    const int swz  = lrow & 7;    // per-lane read swizzle (row&7 == lrow&7)

    // ---- T1: chunked XCD remap (bijective since nwg % 8 == 0 here)
    const int gx  = gridDim.x;
    const int nwg = gx * gridDim.y;
    int bid = blockIdx.y * gx + blockIdx.x;
    if ((nwg & 7) == 0) {
        const int cpx = nwg >> 3;
        bid = (bid & 7) * cpx + (bid >> 3);
    }
    const int bx = bid % gx;
    const int by = bid / gx;

    const int col0 = bx * BN;   // x = column blocks (fast within chunk)
    const int row0 = by * BM;
    const int wm = (wave >> 1) * 64;    // wave tile: 64x64
    const int wn = (wave & 1) * 64;

    // staging: lane l fetches global chunk (l&7)^(l>>3) of row (l>>3)
    const int srow = lane >> 3;                 // row within 8-row group
    const int gchk = (lane & 7) ^ srow;         // permuted global chunk

    f32x4 acc[4][4] = {};

    const bf16_t* Bt = B + (size_t)col0 * K;

    // ---- staging helpers -------------------------------------------------
    auto stageB = [&](bf16_t* dst, int k0) {
        const bf16_t* g = Bt + (size_t)(wave * 32 + srow) * K + k0 + gchk * 8;
        bf16_t* l = dst + (wave * 32) * BK;
        #pragma unroll
        for (int c = 0; c < 4; ++c) {
            gload_lds16(g, l);
            g += (size_t)8 * K;
            l += 8 * BK;
        }
    };
    auto stageA_bf16 = [&](bf16_t* dst, int k0) {
        const bf16_t* Ab = (const bf16_t*)Av;
        const bf16_t* g = Ab + (size_t)(row0 + wave * 32 + srow) * K + k0 + gchk * 8;
        bf16_t* l = dst + (wave * 32) * BK;
        #pragma unroll
        for (int c = 0; c < 4; ++c) {
            gload_lds16(g, l);
            g += (size_t)8 * K;
            l += 8 * BK;
        }
    };
    // fp32-A: issue loads (T14 issue-early) ...
    float4 av[8];
    auto loadA_f32 = [&](int k0) {
        const float* Af = (const float*)Av;
        #pragma unroll
        for (int c = 0; c < 8; ++c) {
            const int e = c * 1024 + tid * 4;
            const int r = e >> 6;
            const int k = e & 63;
            av[c] = *(const float4*)(Af + (size_t)(row0 + r) * K + k0 + k);
        }
    };
    // ... and convert + swizzled ds_write late (after the MFMA phase)
    auto writeA_f32 = [&](bf16_t* dst) {
        #pragma unroll
        for (int c = 0; c < 8; ++c) {
            const int e = c * 1024 + tid * 4;
            const int r = e >> 6;
            const int k = e & 63;
            u16x4 h;
            h.x = f2bf_rne(av[c].x); h.y = f2bf_rne(av[c].y);
            h.z = f2bf_rne(av[c].z); h.w = f2bf_rne(av[c].w);
            const int off = r * BK + (((k >> 3) ^ (r & 7)) << 3) + (k & 7);
            *(u16x4*)(dst + off) = h;
        }
    };

    // ---- prologue: stage tile 0 into buffer 0 ----------------------------
    stageB(lB[0], 0);
    if constexpr (A_IS_FP32) {
        loadA_f32(0);
        writeA_f32(lA[0]);
    } else {
        stageA_bf16(lA[0], 0);
    }
    __syncthreads();

    const int nt = K / BK;
    int cur = 0;

    for (int t = 0; t < nt; ++t) {
        const bool pf = (t + 1 < nt);
        const int knext = (t + 1) * BK;

        // ---- issue next tile's staging BEFORE compute (latency hides under MFMA)
        if (pf) {
            stageB(lB[cur ^ 1], knext);               // global_load_lds (vmcnt)
            if constexpr (A_IS_FP32)
                loadA_f32(knext);                     // into regs (vmcnt)
            else
                stageA_bf16(lA[cur ^ 1], knext);
        }

        // ---- compute on current buffer: 32 MFMAs (2 kk-steps of 16)
        const bf16_t* cA = lA[cur];
        const bf16_t* cB = lB[cur];
        #pragma unroll
        for (int kk = 0; kk < BK; kk += 32) {
            const int cks = (kk >> 3);   // base chunk of this kk-step
            bf16x8 af[4], bfr[4];
            #pragma unroll
            for (int i = 0; i < 4; ++i) {
                const int r = wm + i * 16 + lrow;
                af[i] = *(const bf16x8*)(cA + r * BK + (((cks + quad) ^ swz) << 3));
            }
            #pragma unroll
            for (int j = 0; j < 4; ++j) {
                const int r = wn + j * 16 + lrow;
                bfr[j] = *(const bf16x8*)(cB + r * BK + (((cks + quad) ^ swz) << 3));
            }
            #pragma unroll
            for (int i = 0; i < 4; ++i) {
                #pragma unroll
                for (int j = 0; j < 4; ++j)
                    acc[i][j] = __builtin_amdgcn_mfma_f32_16x16x32_bf16(af[i], bfr[j], acc[i][j], 0, 0, 0);
            }
        }

        // ---- fp32-A: write next tile to LDS now (loads have landed under MFMA)
        if (pf) {
            if constexpr (A_IS_FP32)
                writeA_f32(lA[cur ^ 1]);
        }

        __syncthreads();   // drains vmcnt/lgkm AFTER compute -> hidden
        cur ^= 1;
    }

    // ---- epilogue: bias + exact-erf GELU + store.
    // C/D layout (16x16x32): col = lane&15, row = quad*4 + reg  [m89/m91]
    // j innermost: 4 adjacent 32B segments of one row stored back-to-back.
    float bv[4];
    #pragma unroll
    for (int j = 0; j < 4; ++j) bv[j] = bias[col0 + wn + j * 16 + lrow];

    #pragma unroll
    for (int i = 0; i < 4; ++i) {
        #pragma unroll
        for (int r = 0; r < 4; ++r) {
            const size_t row = (size_t)(row0 + wm + i * 16 + quad * 4 + r);
            #pragma unroll
            for (int j = 0; j < 4; ++j) {
                const int col = col0 + wn + j * 16 + lrow;
                float v = acc[i][j][r] + bv[j];
                v = gelu_erf(v);
                if constexpr (OUT_BF16)
                    ((unsigned short*)Cv)[row * N + col] = f2bf_rne(v);
                else
                    ((float*)Cv)[row * N + col] = v;
            }
        }
    }
}

__global__ void cvt_f32_to_bf16(const float* __restrict__ s,
                                unsigned short* __restrict__ d, int n4)
{
    const int i = blockIdx.x * 256 + threadIdx.x;
    if (i < n4) {
        const float4 v = ((const float4*)s)[i];
        u16x4 h;
        h.x = f2bf_rne(v.x); h.y = f2bf_rne(v.y);
        h.z = f2bf_rne(v.z); h.w = f2bf_rne(v.w);
        ((u16x4*)d)[i] = h;
    }
}

extern "C" void kernel_launch(void* const* d_in, const int* in_sizes, int n_in,
                              void* d_out, int out_size, void* d_ws, size_t ws_size,
                              hipStream_t stream)
{
    const int BATCH = 131072, OBS = 1024, H1 = 512, H2 = 512, H3 = 256;

    const float* obs = (const float*)d_in[0];
    const float* W1  = (const float*)d_in[1];
    const float* b1  = (const float*)d_in[2];
    const float* W2  = (const float*)d_in[3];
    const float* b2  = (const float*)d_in[4];
    const float* W3  = (const float*)d_in[5];
    const float* b3  = (const float*)d_in[6];
    float* out = (float*)d_out;

    // workspace layout (~258 MB): x1 | x2 | W1b | W2b | W3b
    char* ws = (char*)d_ws;
    bf16_t* x1  = (bf16_t*)ws;                                       // BATCH*H1
    bf16_t* x2  = (bf16_t*)(ws + (size_t)BATCH * H1 * 2);            // BATCH*H2
    bf16_t* w1b = (bf16_t*)(ws + (size_t)BATCH * (H1 + H2) * 2);
    bf16_t* w2b = w1b + (size_t)H1 * OBS;
    bf16_t* w3b = w2b + (size_t)H2 * H1;

    // weight fp32 -> bf16 (tiny)
    cvt_f32_to_bf16<<<dim3((H1 * OBS / 4 + 255) / 256), 256, 0, stream>>>(W1, (unsigned short*)w1b, H1 * OBS / 4);
    cvt_f32_to_bf16<<<dim3((H2 * H1 / 4 + 255) / 256), 256, 0, stream>>>(W2, (unsigned short*)w2b, H2 * H1 / 4);
    cvt_f32_to_bf16<<<dim3((H3 * H2 / 4 + 255) / 256), 256, 0, stream>>>(W3, (unsigned short*)w3b, H3 * H2 / 4);

    // L1: obs(fp32) @ W1^T -> x1 (bf16)    grid: (cols fast, rows slow)
    gemm_bias_gelu<true, true><<<dim3(H1 / BN, BATCH / BM), 256, 0, stream>>>(
        obs, w1b, b1, x1, BATCH, H1, OBS);
    // L2: x1 @ W2^T -> x2 (bf16)
    gemm_bias_gelu<false, true><<<dim3(H2 / BN, BATCH / BM), 256, 0, stream>>>(
        x1, w2b, b2, x2, BATCH, H2, H1);
    // L3: x2 @ W3^T -> out (fp32)
    gemm_bias_gelu<false, false><<<dim3(H3 / BN, BATCH / BM), 256, 0, stream>>>(
        x2, w3b, b3, out, BATCH, H3, H2);
}